// Round 4
// baseline (659.525 us; speedup 1.0000x reference)
//
#include <hip/hip_runtime.h>
#include <hip/hip_bf16.h>
#include <hip/hip_fp16.h>
#include <math.h>

#define LEAK 0.2f

typedef _Float16 f16;
typedef _Float16 f16x2 __attribute__((ext_vector_type(2)));
typedef _Float16 f16x4 __attribute__((ext_vector_type(4)));
typedef _Float16 f16x8 __attribute__((ext_vector_type(8)));
typedef float f32x2 __attribute__((ext_vector_type(2)));
typedef float f32x4 __attribute__((ext_vector_type(4)));

__device__ inline unsigned char f32_to_fp8(float v) {
  int p = __builtin_amdgcn_cvt_pk_fp8_f32(v, v, 0, false);
  return (unsigned char)(p & 0xff);
}

// ---------------------------------------------------------------------------
// MFMA GEMM: C[M,NC] = A[M,K] @ B[K,NC] (fp32 in, fp16 or fp8 out, fp32 acc),
// with fused per-(row,head) attention logits asrc/adst (computed from fp32
// accumulators -> unaffected by output quantization).
// Block 256 = 4 waves; tile 64(M) x 64(N); wave w owns rows [w*16, w*16+16).
// Frag layouts (m89-verified): A[m=lane&15][k=(lane>>4)*8+j], B[n][k] same,
// C/D: col=lane&15, row=(lane>>4)*4+reg.
// ---------------------------------------------------------------------------
template <int K, int DH, bool FP8OUT>
__global__ __launch_bounds__(256) void gemm_att_mfma_k(
    const float* __restrict__ A, const float* __restrict__ B,
    void* __restrict__ Cout, const float* __restrict__ a_src,
    const float* __restrict__ a_dst, float* __restrict__ asrc,
    float* __restrict__ adst, int M, int NC) {
  constexpr int KP = K + 8;  // padded stride (halves)
  __shared__ f16 As[64 * KP];
  __shared__ f16 Bs[64 * KP];
  const int tid = threadIdx.x;
  const int row0 = blockIdx.y * 64;
  const int col0 = blockIdx.x * 64;

  // ---- stage A (64 x K), fp32 -> fp16 ----
#pragma unroll
  for (int j = 0; j < K / 16; ++j) {
    int idx = j * 256 + tid;
    int r = idx / (K / 4);
    int k4 = idx % (K / 4);
    int grow = row0 + r;
    float4 v = make_float4(0.f, 0.f, 0.f, 0.f);
    if (grow < M) v = *(const float4*)(A + (size_t)grow * K + k4 * 4);
    f16x4 h = {(f16)v.x, (f16)v.y, (f16)v.z, (f16)v.w};
    *(f16x4*)&As[r * KP + k4 * 4] = h;
  }
  // ---- stage B (K x 64) transposed into Bs[n][k] ----
#pragma unroll
  for (int j = 0; j < K / 16; ++j) {
    int idx = j * 256 + tid;
    int kk = idx / 16;
    int n4 = (idx % 16) * 4;
    float4 v = *(const float4*)(B + (size_t)kk * NC + col0 + n4);
    Bs[(n4 + 0) * KP + kk] = (f16)v.x;
    Bs[(n4 + 1) * KP + kk] = (f16)v.y;
    Bs[(n4 + 2) * KP + kk] = (f16)v.z;
    Bs[(n4 + 3) * KP + kk] = (f16)v.w;
  }
  __syncthreads();

  const int wv = tid >> 6;
  const int lane = tid & 63;
  const int l16 = lane & 15;
  const int l4 = lane >> 4;

  f32x4 acc[4];
#pragma unroll
  for (int ct = 0; ct < 4; ++ct) acc[ct] = (f32x4){0.f, 0.f, 0.f, 0.f};

  const f16* ap = &As[(wv * 16 + l16) * KP + l4 * 8];
#pragma unroll
  for (int kt = 0; kt < K / 32; ++kt) {
    f16x8 av = *(const f16x8*)(ap + kt * 32);
#pragma unroll
    for (int ct = 0; ct < 4; ++ct) {
      f16x8 bv = *(const f16x8*)(&Bs[(ct * 16 + l16) * KP + l4 * 8 + kt * 32]);
      acc[ct] = __builtin_amdgcn_mfma_f32_16x16x32_f16(av, bv, acc[ct], 0, 0, 0);
    }
  }

  // ---- epilogue: store + fused attention logits ----
  constexpr int HPB = 64 / DH;  // heads per block
  constexpr int CTH = DH / 16;  // col-tiles per head
  float ps[HPB][4], pd[HPB][4];
#pragma unroll
  for (int hl = 0; hl < HPB; ++hl)
#pragma unroll
    for (int r = 0; r < 4; ++r) { ps[hl][r] = 0.f; pd[hl][r] = 0.f; }

#pragma unroll
  for (int ct = 0; ct < 4; ++ct) {
    int col = col0 + ct * 16 + l16;
    float vs = a_src[col];
    float vd = a_dst[col];
    int hl = ct / CTH;
#pragma unroll
    for (int r = 0; r < 4; ++r) {
      ps[hl][r] += acc[ct][r] * vs;
      pd[hl][r] += acc[ct][r] * vd;
      int grow = row0 + wv * 16 + l4 * 4 + r;
      if (grow < M) {
        if (FP8OUT) {
          ((unsigned char*)Cout)[(size_t)grow * NC + col] = f32_to_fp8(acc[ct][r]);
        } else {
          ((f16*)Cout)[(size_t)grow * NC + col] = (f16)acc[ct][r];
        }
      }
    }
  }

#pragma unroll
  for (int hl = 0; hl < HPB; ++hl) {
#pragma unroll
    for (int r = 0; r < 4; ++r) {
      float s = ps[hl][r], d = pd[hl][r];
#pragma unroll
      for (int m = 1; m < 16; m <<= 1) {
        s += __shfl_xor(s, m, 64);
        d += __shfl_xor(d, m, 64);
      }
      if (l16 == 0) {
        int grow = row0 + wv * 16 + l4 * 4 + r;
        int h = (col0 / DH) + hl;
        if (grow < M) {
          asrc[(size_t)grow * 8 + h] = s;
          adst[(size_t)grow * 8 + h] = d;
        }
      }
    }
  }
}

// ---------------------------------------------------------------------------
// CSR build
// ---------------------------------------------------------------------------
__global__ void init_counts_k(int* counts, int N) {
  int i = blockIdx.x * blockDim.x + threadIdx.x;
  if (i < N) counts[i] = 1;  // self loop
}

__global__ void count_edges_k(const int* __restrict__ dst, int E, int* counts) {
  int e = blockIdx.x * blockDim.x + threadIdx.x;
  if (e < E) atomicAdd(&counts[dst[e]], 1);
}

__global__ __launch_bounds__(1024) void scan_blocks_k(const int* __restrict__ counts,
                                                      int* __restrict__ offsets,
                                                      int* __restrict__ partials, int N) {
  __shared__ int sd[1024];
  int i = blockIdx.x * 1024 + threadIdx.x;
  int v = (i < N) ? counts[i] : 0;
  sd[threadIdx.x] = v;
  __syncthreads();
  for (int off = 1; off < 1024; off <<= 1) {
    int t = (threadIdx.x >= off) ? sd[threadIdx.x - off] : 0;
    __syncthreads();
    sd[threadIdx.x] += t;
    __syncthreads();
  }
  if (i < N) offsets[i] = sd[threadIdx.x] - v;
  if (threadIdx.x == 1023) partials[blockIdx.x] = sd[1023];
}

__global__ __launch_bounds__(1024) void scan_partials_k(int* partials, int nb) {
  __shared__ int sd[1024];
  int i = threadIdx.x;
  int v = (i < nb) ? partials[i] : 0;
  sd[i] = v;
  __syncthreads();
  for (int off = 1; off < 1024; off <<= 1) {
    int t = (i >= off) ? sd[i - off] : 0;
    __syncthreads();
    sd[i] += t;
    __syncthreads();
  }
  if (i < nb) partials[i] = sd[i] - v;
}

__global__ __launch_bounds__(1024) void add_offsets_k(int* __restrict__ offsets,
                                                      const int* __restrict__ partials,
                                                      int* __restrict__ cursor, int N, int M) {
  int i = blockIdx.x * 1024 + threadIdx.x;
  if (i < N) {
    int o = offsets[i] + partials[blockIdx.x];
    offsets[i] = o;
    cursor[i] = o;
  }
  if (i == 0) offsets[N] = M;
}

__global__ void fill_csr_k(const int* __restrict__ ei, int E, int N,
                           int* __restrict__ cursor, int* __restrict__ csr) {
  int i = blockIdx.x * blockDim.x + threadIdx.x;
  if (i >= E + N) return;
  int s, d;
  if (i < E) {
    s = ei[i];
    d = ei[E + i];
  } else {
    s = d = i - E;
  }
  int pos = atomicAdd(&cursor[d], 1);
  csr[pos] = s;
}

// ---------------------------------------------------------------------------
// Per-edge, per-head softmax weights, dst-parallel: 8 lanes = 8 heads per dst
// node; dst derived from offsets (no dstv array). w16[p][h] = exp(leaky(e)).
// No max-subtraction: e ~ N(0,2), extreme tail < 11 -> fp16 safe (max 65504).
// ---------------------------------------------------------------------------
__global__ __launch_bounds__(256) void edge_w_k(const int* __restrict__ csr,
                                                const int* __restrict__ offsets,
                                                const float* __restrict__ asrc,
                                                const float* __restrict__ adst,
                                                f16* __restrict__ w16, int N) {
  int t = blockIdx.x * 256 + threadIdx.x;
  int n = t >> 3;
  int h = t & 7;
  if (n >= N) return;
  int off = offsets[n], end = offsets[n + 1];
  float ad = adst[(size_t)n * 8 + h];
  for (int p = off; p < end; ++p) {
    int s = csr[p];  // broadcast within the 8-lane group
    float e = asrc[(size_t)s * 8 + h] + ad;
    e = e > 0.f ? e : LEAK * e;
    w16[(size_t)p * 8 + h] = (f16)__expf(e);
  }
}

// ---------------------------------------------------------------------------
// Layer-1 aggregation: one wave per dst node; weights precomputed; messages
// in fp8 e4m3 (row = 256 B -> 1 uint/lane = 4 elems). Epilogue: mean heads +
// b1 + ELU -> hout[n][32] fp32.
// ---------------------------------------------------------------------------
__global__ __launch_bounds__(256) void aggregate1_k(const unsigned char* __restrict__ xh8,
                                                    const f16* __restrict__ w16,
                                                    const int* __restrict__ offsets,
                                                    const int* __restrict__ csr,
                                                    const float* __restrict__ b1,
                                                    float* __restrict__ hout, int N) {
  const int lane = threadIdx.x & 63;
  const int n = blockIdx.x * 4 + (threadIdx.x >> 6);
  if (n >= N) return;
  const int off = offsets[n];
  const int deg = offsets[n + 1] - off;
  const int h = lane >> 3;
  const int* cp = csr + off;
  const f16* wp = w16 + (size_t)off * 8 + h;
  const unsigned int* xw = (const unsigned int*)xh8;  // row = 64 words

  float acc0 = 0.f, acc1 = 0.f, acc2 = 0.f, acc3 = 0.f, dsum = 0.f;
#pragma unroll 4
  for (int i = 0; i < deg; ++i) {
    int s = cp[i];
    float w = (float)wp[(size_t)i * 8];
    unsigned int b = xw[(size_t)s * 64 + lane];
    f32x2 lo = __builtin_amdgcn_cvt_pk_f32_fp8(b, false);
    f32x2 hi = __builtin_amdgcn_cvt_pk_f32_fp8(b, true);
    acc0 += w * lo.x;
    acc1 += w * lo.y;
    acc2 += w * hi.x;
    acc3 += w * hi.y;
    dsum += w;
  }
  float inv = 1.0f / dsum;
  acc0 *= inv; acc1 *= inv; acc2 *= inv; acc3 *= inv;

  // mean over heads: sum lanes with equal (lane & 7)
#pragma unroll
  for (int m = 8; m < 64; m <<= 1) {
    acc0 += __shfl_xor(acc0, m, 64);
    acc1 += __shfl_xor(acc1, m, 64);
    acc2 += __shfl_xor(acc2, m, 64);
    acc3 += __shfl_xor(acc3, m, 64);
  }
  if (lane < 8) {
    int d = lane * 4;
    float4 bv = *(const float4*)(b1 + d);
    float o0 = acc0 * 0.125f + bv.x;
    float o1 = acc1 * 0.125f + bv.y;
    float o2 = acc2 * 0.125f + bv.z;
    float o3 = acc3 * 0.125f + bv.w;
    o0 = o0 > 0.f ? o0 : expm1f(o0);
    o1 = o1 > 0.f ? o1 : expm1f(o1);
    o2 = o2 > 0.f ? o2 : expm1f(o2);
    o3 = o3 > 0.f ? o3 : expm1f(o3);
    *(float4*)(hout + (size_t)n * 32 + d) = make_float4(o0, o1, o2, o3);
  }
}

// ---------------------------------------------------------------------------
// Layer-2 aggregation + log_softmax. xh row = 128 f16 -> 2 halves/lane.
// ---------------------------------------------------------------------------
__global__ __launch_bounds__(256) void aggregate2_k(const f16* __restrict__ xh,
                                                    const f16* __restrict__ w16,
                                                    const int* __restrict__ offsets,
                                                    const int* __restrict__ csr,
                                                    const float* __restrict__ b2,
                                                    float* __restrict__ out, int N) {
  const int lane = threadIdx.x & 63;
  const int n = blockIdx.x * 4 + (threadIdx.x >> 6);
  if (n >= N) return;
  const int off = offsets[n];
  const int deg = offsets[n + 1] - off;
  const int h = lane >> 3;
  const int cbase = lane * 2;
  const int* cp = csr + off;
  const f16* wp = w16 + (size_t)off * 8 + h;

  float acc0 = 0.f, acc1 = 0.f, dsum = 0.f;
#pragma unroll 4
  for (int i = 0; i < deg; ++i) {
    int s = cp[i];
    float w = (float)wp[(size_t)i * 8];
    f16x2 v = *(const f16x2*)(xh + (size_t)s * 128 + cbase);
    acc0 += w * (float)v[0];
    acc1 += w * (float)v[1];
    dsum += w;
  }
  float inv = 1.0f / dsum;
  acc0 *= inv; acc1 *= inv;

#pragma unroll
  for (int m = 8; m < 64; m <<= 1) {
    acc0 += __shfl_xor(acc0, m, 64);
    acc1 += __shfl_xor(acc1, m, 64);
  }
  int c = (lane & 7) * 2;
  float l0 = acc0 * 0.125f + b2[c];
  float l1 = acc1 * 0.125f + b2[c + 1];

  float m2 = fmaxf(l0, l1);
#pragma unroll
  for (int m = 1; m < 8; m <<= 1) m2 = fmaxf(m2, __shfl_xor(m2, m, 64));
  float es = __expf(l0 - m2) + __expf(l1 - m2);
#pragma unroll
  for (int m = 1; m < 8; m <<= 1) es += __shfl_xor(es, m, 64);
  float lse = logf(es) + m2;

  if (lane < 8) {
    *(float2*)(out + (size_t)n * 16 + c) = make_float2(l0 - lse, l1 - lse);
    *(float2*)(out + (size_t)N * 16 + (size_t)n * 16 + c) = make_float2(l0, l1);
  }
}

// ---------------------------------------------------------------------------
extern "C" void kernel_launch(void* const* d_in, const int* in_sizes, int n_in,
                              void* d_out, int out_size, void* d_ws, size_t ws_size,
                              hipStream_t stream) {
  const float* x      = (const float*)d_in[0];
  const int*   ei     = (const int*)d_in[1];
  const float* W1     = (const float*)d_in[2];
  const float* a_src1 = (const float*)d_in[3];
  const float* a_dst1 = (const float*)d_in[4];
  const float* b1     = (const float*)d_in[5];
  const float* W2     = (const float*)d_in[6];
  const float* a_src2 = (const float*)d_in[7];
  const float* a_dst2 = (const float*)d_in[8];
  const float* b2     = (const float*)d_in[9];

  const int N = in_sizes[0] / 128;  // F = 128
  const int E = in_sizes[1] / 2;
  const int M = E + N;

  char* w = (char*)d_ws;
  size_t used = 0;
  auto alloc = [&](size_t bytes) -> void* {
    size_t aligned = (bytes + 255) & ~(size_t)255;
    void* p = w + used;
    used += aligned;
    return p;
  };
  unsigned char* xh1q = (unsigned char*)alloc((size_t)N * 256);  // fp8
  f16*   xh2h   = (f16*)alloc((size_t)N * 128 * 2);
  f16*   w16a   = (f16*)alloc((size_t)M * 8 * 2);
  f16*   w16b   = (f16*)alloc((size_t)M * 8 * 2);
  float* hbuf   = (float*)alloc((size_t)N * 32 * 4);
  float* asrc1  = (float*)alloc((size_t)N * 8 * 4);
  float* adst1  = (float*)alloc((size_t)N * 8 * 4);
  float* asrc2  = (float*)alloc((size_t)N * 8 * 4);
  float* adst2  = (float*)alloc((size_t)N * 8 * 4);
  int*   counts = (int*)alloc((size_t)N * 4);
  int*   offs   = (int*)alloc((size_t)(N + 1) * 4);
  int*   cursor = (int*)alloc((size_t)N * 4);
  int*   parts  = (int*)alloc(1024 * 4);
  int*   csr    = (int*)alloc((size_t)M * 4);
  (void)ws_size;

  float* out = (float*)d_out;
  const int gy = (N + 63) / 64;

  // ---- Layer 1 linear (MFMA) + fused att logits + fp8 store ----
  gemm_att_mfma_k<128, 32, true><<<dim3(4, gy), 256, 0, stream>>>(
      x, W1, xh1q, a_src1, a_dst1, asrc1, adst1, N, 256);

  // ---- CSR build ----
  init_counts_k<<<(N + 255) / 256, 256, 0, stream>>>(counts, N);
  count_edges_k<<<(E + 255) / 256, 256, 0, stream>>>(ei + E, E, counts);
  int nb = (N + 1023) / 1024;
  scan_blocks_k<<<nb, 1024, 0, stream>>>(counts, offs, parts, N);
  scan_partials_k<<<1, 1024, 0, stream>>>(parts, nb);
  add_offsets_k<<<nb, 1024, 0, stream>>>(offs, parts, cursor, N, M);
  fill_csr_k<<<(M + 255) / 256, 256, 0, stream>>>(ei, E, N, cursor, csr);

  // ---- Layer 1 edge weights + aggregation -> h ----
  edge_w_k<<<((size_t)N * 8 + 255) / 256, 256, 0, stream>>>(csr, offs, asrc1, adst1, w16a, N);
  aggregate1_k<<<(N + 3) / 4, 256, 0, stream>>>(xh1q, w16a, offs, csr, b1, hbuf, N);

  // ---- Layer 2 ----
  gemm_att_mfma_k<32, 16, false><<<dim3(2, gy), 256, 0, stream>>>(
      hbuf, W2, xh2h, a_src2, a_dst2, asrc2, adst2, N, 128);
  edge_w_k<<<((size_t)N * 8 + 255) / 256, 256, 0, stream>>>(csr, offs, asrc2, adst2, w16b, N);
  aggregate2_k<<<(N + 3) / 4, 256, 0, stream>>>(xh2h, w16b, offs, csr, b2, out, N);
}

// Round 5
// 651.603 us; speedup vs baseline: 1.0122x; 1.0122x over previous
//
#include <hip/hip_runtime.h>
#include <hip/hip_bf16.h>
#include <hip/hip_fp16.h>
#include <math.h>

#define LEAK 0.2f

typedef _Float16 f16;
typedef _Float16 f16x2 __attribute__((ext_vector_type(2)));
typedef _Float16 f16x4 __attribute__((ext_vector_type(4)));
typedef _Float16 f16x8 __attribute__((ext_vector_type(8)));
typedef float f32x2 __attribute__((ext_vector_type(2)));
typedef float f32x4 __attribute__((ext_vector_type(4)));

__device__ inline unsigned char f32_to_fp8(float v) {
  int p = __builtin_amdgcn_cvt_pk_fp8_f32(v, v, 0, false);
  return (unsigned char)(p & 0xff);
}

// ---------------------------------------------------------------------------
// HYBRID kernel: even blocks = MFMA GEMM tile (C=A@B, fp32 in, fp16/fp8 out,
// fused per-(row,head) attention logits); odd blocks = CSR fill scatter
// (latency-bound, co-scheduled to hide under the GEMM's MFMA/LDS work).
// GEMM: block 256 = 4 waves; tile 64(M) x 64(N); wave w owns rows w*16..+16.
// Frag layouts (m89-verified): A[m=lane&15][k=(lane>>4)*8+j], B[n][k] same,
// C/D: col=lane&15, row=(lane>>4)*4+reg.
// ---------------------------------------------------------------------------
template <int K, int DH, bool FP8OUT, int GX>
__global__ __launch_bounds__(256) void gemm_fill_k(
    const float* __restrict__ A, const float* __restrict__ B,
    void* __restrict__ Cout, const float* __restrict__ a_src,
    const float* __restrict__ a_dst, float* __restrict__ asrc,
    float* __restrict__ adst, int M, int NC,
    const int* __restrict__ ei, int E, int Nn,
    int* __restrict__ cursor, uint2* __restrict__ csr2) {
  constexpr int KP = K + 8;  // padded stride (halves)
  __shared__ f16 As[64 * KP];
  __shared__ f16 Bs[64 * KP];
  const int bid = blockIdx.x;

  if (bid & 1) {
    // ---- fill role: grid-stride scatter of (src,dst) into CSR slots ----
    const int nFill = (int)(gridDim.x >> 1);
    const int Mtot = E + Nn;
    for (int i = (bid >> 1) * 256 + threadIdx.x; i < Mtot; i += nFill * 256) {
      int s, d;
      if (i < E) {
        s = ei[i];
        d = ei[E + i];
      } else {
        s = d = i - E;
      }
      int pos = atomicAdd(&cursor[d], 1);
      csr2[pos] = make_uint2((unsigned)s, (unsigned)d);
    }
    return;
  }

  const int g = bid >> 1;
  const int tid = threadIdx.x;
  const int row0 = (g / GX) * 64;
  const int col0 = (g % GX) * 64;

  // ---- stage A (64 x K), fp32 -> fp16 ----
#pragma unroll
  for (int j = 0; j < K / 16; ++j) {
    int idx = j * 256 + tid;
    int r = idx / (K / 4);
    int k4 = idx % (K / 4);
    int grow = row0 + r;
    float4 v = make_float4(0.f, 0.f, 0.f, 0.f);
    if (grow < M) v = *(const float4*)(A + (size_t)grow * K + k4 * 4);
    f16x4 h = {(f16)v.x, (f16)v.y, (f16)v.z, (f16)v.w};
    *(f16x4*)&As[r * KP + k4 * 4] = h;
  }
  // ---- stage B (K x 64) transposed into Bs[n][k] ----
#pragma unroll
  for (int j = 0; j < K / 16; ++j) {
    int idx = j * 256 + tid;
    int kk = idx / 16;
    int n4 = (idx % 16) * 4;
    float4 v = *(const float4*)(B + (size_t)kk * NC + col0 + n4);
    Bs[(n4 + 0) * KP + kk] = (f16)v.x;
    Bs[(n4 + 1) * KP + kk] = (f16)v.y;
    Bs[(n4 + 2) * KP + kk] = (f16)v.z;
    Bs[(n4 + 3) * KP + kk] = (f16)v.w;
  }
  __syncthreads();

  const int wv = tid >> 6;
  const int lane = tid & 63;
  const int l16 = lane & 15;
  const int l4 = lane >> 4;

  f32x4 acc[4];
#pragma unroll
  for (int ct = 0; ct < 4; ++ct) acc[ct] = (f32x4){0.f, 0.f, 0.f, 0.f};

  const f16* ap = &As[(wv * 16 + l16) * KP + l4 * 8];
#pragma unroll
  for (int kt = 0; kt < K / 32; ++kt) {
    f16x8 av = *(const f16x8*)(ap + kt * 32);
#pragma unroll
    for (int ct = 0; ct < 4; ++ct) {
      f16x8 bv = *(const f16x8*)(&Bs[(ct * 16 + l16) * KP + l4 * 8 + kt * 32]);
      acc[ct] = __builtin_amdgcn_mfma_f32_16x16x32_f16(av, bv, acc[ct], 0, 0, 0);
    }
  }

  // ---- epilogue: store + fused attention logits (from fp32 acc) ----
  constexpr int HPB = 64 / DH;  // heads per block
  constexpr int CTH = DH / 16;  // col-tiles per head
  float ps[HPB][4], pd[HPB][4];
#pragma unroll
  for (int hl = 0; hl < HPB; ++hl)
#pragma unroll
    for (int r = 0; r < 4; ++r) { ps[hl][r] = 0.f; pd[hl][r] = 0.f; }

#pragma unroll
  for (int ct = 0; ct < 4; ++ct) {
    int col = col0 + ct * 16 + l16;
    float vs = a_src[col];
    float vd = a_dst[col];
    int hl = ct / CTH;
#pragma unroll
    for (int r = 0; r < 4; ++r) {
      ps[hl][r] += acc[ct][r] * vs;
      pd[hl][r] += acc[ct][r] * vd;
      int grow = row0 + wv * 16 + l4 * 4 + r;
      if (grow < M) {
        if (FP8OUT) {
          ((unsigned char*)Cout)[(size_t)grow * NC + col] = f32_to_fp8(acc[ct][r]);
        } else {
          ((f16*)Cout)[(size_t)grow * NC + col] = (f16)acc[ct][r];
        }
      }
    }
  }

#pragma unroll
  for (int hl = 0; hl < HPB; ++hl) {
#pragma unroll
    for (int r = 0; r < 4; ++r) {
      float s = ps[hl][r], d = pd[hl][r];
#pragma unroll
      for (int m = 1; m < 16; m <<= 1) {
        s += __shfl_xor(s, m, 64);
        d += __shfl_xor(d, m, 64);
      }
      if (l16 == 0) {
        int grow = row0 + wv * 16 + l4 * 4 + r;
        int h = (col0 / DH) + hl;
        if (grow < M) {
          asrc[(size_t)grow * 8 + h] = s;
          adst[(size_t)grow * 8 + h] = d;
        }
      }
    }
  }
}

// Plain GEMM (layer 2, no fill partner)
template <int K, int DH, bool FP8OUT>
__global__ __launch_bounds__(256) void gemm_att_mfma_k(
    const float* __restrict__ A, const float* __restrict__ B,
    void* __restrict__ Cout, const float* __restrict__ a_src,
    const float* __restrict__ a_dst, float* __restrict__ asrc,
    float* __restrict__ adst, int M, int NC) {
  constexpr int KP = K + 8;
  __shared__ f16 As[64 * KP];
  __shared__ f16 Bs[64 * KP];
  const int tid = threadIdx.x;
  const int row0 = blockIdx.y * 64;
  const int col0 = blockIdx.x * 64;

#pragma unroll
  for (int j = 0; j < K / 16; ++j) {
    int idx = j * 256 + tid;
    int r = idx / (K / 4);
    int k4 = idx % (K / 4);
    int grow = row0 + r;
    float4 v = make_float4(0.f, 0.f, 0.f, 0.f);
    if (grow < M) v = *(const float4*)(A + (size_t)grow * K + k4 * 4);
    f16x4 h = {(f16)v.x, (f16)v.y, (f16)v.z, (f16)v.w};
    *(f16x4*)&As[r * KP + k4 * 4] = h;
  }
#pragma unroll
  for (int j = 0; j < K / 16; ++j) {
    int idx = j * 256 + tid;
    int kk = idx / 16;
    int n4 = (idx % 16) * 4;
    float4 v = *(const float4*)(B + (size_t)kk * NC + col0 + n4);
    Bs[(n4 + 0) * KP + kk] = (f16)v.x;
    Bs[(n4 + 1) * KP + kk] = (f16)v.y;
    Bs[(n4 + 2) * KP + kk] = (f16)v.z;
    Bs[(n4 + 3) * KP + kk] = (f16)v.w;
  }
  __syncthreads();

  const int wv = tid >> 6;
  const int lane = tid & 63;
  const int l16 = lane & 15;
  const int l4 = lane >> 4;

  f32x4 acc[4];
#pragma unroll
  for (int ct = 0; ct < 4; ++ct) acc[ct] = (f32x4){0.f, 0.f, 0.f, 0.f};

  const f16* ap = &As[(wv * 16 + l16) * KP + l4 * 8];
#pragma unroll
  for (int kt = 0; kt < K / 32; ++kt) {
    f16x8 av = *(const f16x8*)(ap + kt * 32);
#pragma unroll
    for (int ct = 0; ct < 4; ++ct) {
      f16x8 bv = *(const f16x8*)(&Bs[(ct * 16 + l16) * KP + l4 * 8 + kt * 32]);
      acc[ct] = __builtin_amdgcn_mfma_f32_16x16x32_f16(av, bv, acc[ct], 0, 0, 0);
    }
  }

  constexpr int HPB = 64 / DH;
  constexpr int CTH = DH / 16;
  float ps[HPB][4], pd[HPB][4];
#pragma unroll
  for (int hl = 0; hl < HPB; ++hl)
#pragma unroll
    for (int r = 0; r < 4; ++r) { ps[hl][r] = 0.f; pd[hl][r] = 0.f; }

#pragma unroll
  for (int ct = 0; ct < 4; ++ct) {
    int col = col0 + ct * 16 + l16;
    float vs = a_src[col];
    float vd = a_dst[col];
    int hl = ct / CTH;
#pragma unroll
    for (int r = 0; r < 4; ++r) {
      ps[hl][r] += acc[ct][r] * vs;
      pd[hl][r] += acc[ct][r] * vd;
      int grow = row0 + wv * 16 + l4 * 4 + r;
      if (grow < M) {
        if (FP8OUT) {
          ((unsigned char*)Cout)[(size_t)grow * NC + col] = f32_to_fp8(acc[ct][r]);
        } else {
          ((f16*)Cout)[(size_t)grow * NC + col] = (f16)acc[ct][r];
        }
      }
    }
  }

#pragma unroll
  for (int hl = 0; hl < HPB; ++hl) {
#pragma unroll
    for (int r = 0; r < 4; ++r) {
      float s = ps[hl][r], d = pd[hl][r];
#pragma unroll
      for (int m = 1; m < 16; m <<= 1) {
        s += __shfl_xor(s, m, 64);
        d += __shfl_xor(d, m, 64);
      }
      if (l16 == 0) {
        int grow = row0 + wv * 16 + l4 * 4 + r;
        int h = (col0 / DH) + hl;
        if (grow < M) {
          asrc[(size_t)grow * 8 + h] = s;
          adst[(size_t)grow * 8 + h] = d;
        }
      }
    }
  }
}

// ---------------------------------------------------------------------------
// CSR build helpers
// ---------------------------------------------------------------------------
__global__ void count_edges_k(const int* __restrict__ dst, int E, int* counts) {
  int e = blockIdx.x * blockDim.x + threadIdx.x;
  if (e < E) atomicAdd(&counts[dst[e]], 1);
}

// self-loop folded: per-node degree = counts[i] + 1
__global__ __launch_bounds__(1024) void scan_blocks_k(const int* __restrict__ counts,
                                                      int* __restrict__ offsets,
                                                      int* __restrict__ partials, int N) {
  __shared__ int sd[1024];
  int i = blockIdx.x * 1024 + threadIdx.x;
  int v = (i < N) ? counts[i] + 1 : 0;
  sd[threadIdx.x] = v;
  __syncthreads();
  for (int off = 1; off < 1024; off <<= 1) {
    int t = (threadIdx.x >= off) ? sd[threadIdx.x - off] : 0;
    __syncthreads();
    sd[threadIdx.x] += t;
    __syncthreads();
  }
  if (i < N) offsets[i] = sd[threadIdx.x] - v;
  if (threadIdx.x == 1023) partials[blockIdx.x] = sd[1023];
}

__global__ __launch_bounds__(1024) void scan_partials_k(int* partials, int nb) {
  __shared__ int sd[1024];
  int i = threadIdx.x;
  int v = (i < nb) ? partials[i] : 0;
  sd[i] = v;
  __syncthreads();
  for (int off = 1; off < 1024; off <<= 1) {
    int t = (i >= off) ? sd[i - off] : 0;
    __syncthreads();
    sd[i] += t;
    __syncthreads();
  }
  if (i < nb) partials[i] = sd[i] - v;
}

__global__ __launch_bounds__(1024) void add_offsets_k(int* __restrict__ offsets,
                                                      const int* __restrict__ partials,
                                                      int* __restrict__ cursor, int N, int M) {
  int i = blockIdx.x * 1024 + threadIdx.x;
  if (i < N) {
    int o = offsets[i] + partials[blockIdx.x];
    offsets[i] = o;
    cursor[i] = o;
  }
  if (i == 0) offsets[N] = M;
}

// ---------------------------------------------------------------------------
// Per-edge, per-head softmax weights (edge-parallel, vectorized f16x8 store).
// w16[p][h] = exp(leaky(asrc[s][h] + adst[d][h])).  No max-subtraction:
// e ~ N(0,2), extreme tail < 11 -> fp16 safe (max 65504).
// ---------------------------------------------------------------------------
__global__ __launch_bounds__(256) void edge_w_k(const uint2* __restrict__ csr2,
                                                const float* __restrict__ asrc,
                                                const float* __restrict__ adst,
                                                f16* __restrict__ w16, int Mtot) {
  int p = blockIdx.x * 256 + threadIdx.x;
  if (p >= Mtot) return;
  uint2 sd = csr2[p];
  const float4* ap = (const float4*)(asrc + (size_t)sd.x * 8);
  const float4* bp = (const float4*)(adst + (size_t)sd.y * 8);
  float4 a0 = ap[0], a1 = ap[1];
  float4 b0 = bp[0], b1 = bp[1];
  float e[8] = {a0.x + b0.x, a0.y + b0.y, a0.z + b0.z, a0.w + b0.w,
                a1.x + b1.x, a1.y + b1.y, a1.z + b1.z, a1.w + b1.w};
  f16x8 o;
#pragma unroll
  for (int i = 0; i < 8; ++i) {
    float t = e[i];
    t = t > 0.f ? t : LEAK * t;
    o[i] = (f16)__expf(t);
  }
  *(f16x8*)(w16 + (size_t)p * 8) = o;
}

// ---------------------------------------------------------------------------
// Layer-1 aggregation: one wave per dst node; weights precomputed; messages
// in fp8 e4m3 (row = 256 B -> 1 uint/lane = 4 elems). Epilogue: mean heads +
// b1 + ELU -> hout[n][32] fp32.
// ---------------------------------------------------------------------------
__global__ __launch_bounds__(256) void aggregate1_k(const unsigned char* __restrict__ xh8,
                                                    const f16* __restrict__ w16,
                                                    const int* __restrict__ offsets,
                                                    const uint2* __restrict__ csr2,
                                                    const float* __restrict__ b1,
                                                    float* __restrict__ hout, int N) {
  const int lane = threadIdx.x & 63;
  const int n = blockIdx.x * 4 + (threadIdx.x >> 6);
  if (n >= N) return;
  const int off = offsets[n];
  const int deg = offsets[n + 1] - off;
  const int h = lane >> 3;
  const uint2* cp = csr2 + off;
  const f16* wp = w16 + (size_t)off * 8 + h;
  const unsigned int* xw = (const unsigned int*)xh8;  // row = 64 words

  float acc0 = 0.f, acc1 = 0.f, acc2 = 0.f, acc3 = 0.f, dsum = 0.f;
#pragma unroll 4
  for (int i = 0; i < deg; ++i) {
    unsigned int s = cp[i].x;
    float w = (float)wp[(size_t)i * 8];
    unsigned int b = xw[(size_t)s * 64 + lane];
    f32x2 lo = __builtin_amdgcn_cvt_pk_f32_fp8(b, false);
    f32x2 hi = __builtin_amdgcn_cvt_pk_f32_fp8(b, true);
    acc0 += w * lo.x;
    acc1 += w * lo.y;
    acc2 += w * hi.x;
    acc3 += w * hi.y;
    dsum += w;
  }
  float inv = 1.0f / dsum;
  acc0 *= inv; acc1 *= inv; acc2 *= inv; acc3 *= inv;

#pragma unroll
  for (int m = 8; m < 64; m <<= 1) {
    acc0 += __shfl_xor(acc0, m, 64);
    acc1 += __shfl_xor(acc1, m, 64);
    acc2 += __shfl_xor(acc2, m, 64);
    acc3 += __shfl_xor(acc3, m, 64);
  }
  if (lane < 8) {
    int d = lane * 4;
    float4 bv = *(const float4*)(b1 + d);
    float o0 = acc0 * 0.125f + bv.x;
    float o1 = acc1 * 0.125f + bv.y;
    float o2 = acc2 * 0.125f + bv.z;
    float o3 = acc3 * 0.125f + bv.w;
    o0 = o0 > 0.f ? o0 : expm1f(o0);
    o1 = o1 > 0.f ? o1 : expm1f(o1);
    o2 = o2 > 0.f ? o2 : expm1f(o2);
    o3 = o3 > 0.f ? o3 : expm1f(o3);
    *(float4*)(hout + (size_t)n * 32 + d) = make_float4(o0, o1, o2, o3);
  }
}

// ---------------------------------------------------------------------------
// Layer-2 aggregation + log_softmax. xh row = 128 f16 -> 2 halves/lane.
// ---------------------------------------------------------------------------
__global__ __launch_bounds__(256) void aggregate2_k(const f16* __restrict__ xh,
                                                    const f16* __restrict__ w16,
                                                    const int* __restrict__ offsets,
                                                    const uint2* __restrict__ csr2,
                                                    const float* __restrict__ b2,
                                                    float* __restrict__ out, int N) {
  const int lane = threadIdx.x & 63;
  const int n = blockIdx.x * 4 + (threadIdx.x >> 6);
  if (n >= N) return;
  const int off = offsets[n];
  const int deg = offsets[n + 1] - off;
  const int h = lane >> 3;
  const int cbase = lane * 2;
  const uint2* cp = csr2 + off;
  const f16* wp = w16 + (size_t)off * 8 + h;

  float acc0 = 0.f, acc1 = 0.f, dsum = 0.f;
#pragma unroll 4
  for (int i = 0; i < deg; ++i) {
    unsigned int s = cp[i].x;
    float w = (float)wp[(size_t)i * 8];
    f16x2 v = *(const f16x2*)(xh + (size_t)s * 128 + cbase);
    acc0 += w * (float)v[0];
    acc1 += w * (float)v[1];
    dsum += w;
  }
  float inv = 1.0f / dsum;
  acc0 *= inv; acc1 *= inv;

#pragma unroll
  for (int m = 8; m < 64; m <<= 1) {
    acc0 += __shfl_xor(acc0, m, 64);
    acc1 += __shfl_xor(acc1, m, 64);
  }
  int c = (lane & 7) * 2;
  float l0 = acc0 * 0.125f + b2[c];
  float l1 = acc1 * 0.125f + b2[c + 1];

  float m2 = fmaxf(l0, l1);
#pragma unroll
  for (int m = 1; m < 8; m <<= 1) m2 = fmaxf(m2, __shfl_xor(m2, m, 64));
  float es = __expf(l0 - m2) + __expf(l1 - m2);
#pragma unroll
  for (int m = 1; m < 8; m <<= 1) es += __shfl_xor(es, m, 64);
  float lse = logf(es) + m2;

  if (lane < 8) {
    *(float2*)(out + (size_t)n * 16 + c) = make_float2(l0 - lse, l1 - lse);
    *(float2*)(out + (size_t)N * 16 + (size_t)n * 16 + c) = make_float2(l0, l1);
  }
}

// ---------------------------------------------------------------------------
extern "C" void kernel_launch(void* const* d_in, const int* in_sizes, int n_in,
                              void* d_out, int out_size, void* d_ws, size_t ws_size,
                              hipStream_t stream) {
  const float* x      = (const float*)d_in[0];
  const int*   ei     = (const int*)d_in[1];
  const float* W1     = (const float*)d_in[2];
  const float* a_src1 = (const float*)d_in[3];
  const float* a_dst1 = (const float*)d_in[4];
  const float* b1     = (const float*)d_in[5];
  const float* W2     = (const float*)d_in[6];
  const float* a_src2 = (const float*)d_in[7];
  const float* a_dst2 = (const float*)d_in[8];
  const float* b2     = (const float*)d_in[9];

  const int N = in_sizes[0] / 128;  // F = 128
  const int E = in_sizes[1] / 2;
  const int M = E + N;

  char* w = (char*)d_ws;
  size_t used = 0;
  auto alloc = [&](size_t bytes) -> void* {
    size_t aligned = (bytes + 255) & ~(size_t)255;
    void* p = w + used;
    used += aligned;
    return p;
  };
  unsigned char* xh1q = (unsigned char*)alloc((size_t)N * 256);  // fp8
  f16*   xh2h   = (f16*)alloc((size_t)N * 128 * 2);
  f16*   w16a   = (f16*)alloc((size_t)M * 8 * 2);
  f16*   w16b   = (f16*)alloc((size_t)M * 8 * 2);
  float* hbuf   = (float*)alloc((size_t)N * 32 * 4);
  float* asrc1  = (float*)alloc((size_t)N * 8 * 4);
  float* adst1  = (float*)alloc((size_t)N * 8 * 4);
  float* asrc2  = (float*)alloc((size_t)N * 8 * 4);
  float* adst2  = (float*)alloc((size_t)N * 8 * 4);
  int*   counts = (int*)alloc((size_t)N * 4);
  int*   offs   = (int*)alloc((size_t)(N + 1) * 4);
  int*   cursor = (int*)alloc((size_t)N * 4);
  int*   parts  = (int*)alloc(1024 * 4);
  uint2* csr2   = (uint2*)alloc((size_t)M * 8);
  (void)ws_size;

  float* out = (float*)d_out;
  const int gy = (N + 63) / 64;

  // ---- CSR prep: zero counts, count, scan ----
  hipMemsetAsync(counts, 0, (size_t)N * 4, stream);
  count_edges_k<<<(E + 255) / 256, 256, 0, stream>>>(ei + E, E, counts);
  int nb = (N + 1023) / 1024;
  scan_blocks_k<<<nb, 1024, 0, stream>>>(counts, offs, parts, N);
  scan_partials_k<<<1, 1024, 0, stream>>>(parts, nb);
  add_offsets_k<<<nb, 1024, 0, stream>>>(offs, parts, cursor, N, M);

  // ---- HYBRID: layer-1 GEMM+att (even blocks) || CSR fill (odd blocks) ----
  gemm_fill_k<128, 32, true, 4><<<2 * 4 * gy, 256, 0, stream>>>(
      x, W1, xh1q, a_src1, a_dst1, asrc1, adst1, N, 256, ei, E, N, cursor, csr2);

  // ---- Layer 1 edge weights + aggregation -> h ----
  edge_w_k<<<(M + 255) / 256, 256, 0, stream>>>(csr2, asrc1, adst1, w16a, M);
  aggregate1_k<<<(N + 3) / 4, 256, 0, stream>>>(xh1q, w16a, offs, csr2, b1, hbuf, N);

  // ---- Layer 2 ----
  gemm_att_mfma_k<32, 16, false><<<dim3(2, gy), 256, 0, stream>>>(
      hbuf, W2, xh2h, a_src2, a_dst2, asrc2, adst2, N, 128);
  edge_w_k<<<(M + 255) / 256, 256, 0, stream>>>(csr2, asrc2, adst2, w16b, M);
  aggregate2_k<<<(N + 3) / 4, 256, 0, stream>>>(xh2h, w16b, offs, csr2, b2, out, N);
}